// Round 6
// baseline (258.851 us; speedup 1.0000x reference)
//
#include <hip/hip_runtime.h>
#include <type_traits>

constexpr int N_N  = 20000;
constexpr int N_E  = 320000;
constexpr int N_ET = N_E + N_N;   // 340000 (self-loops appended)
constexpr int IN_D = 128;
constexpr int HID  = 256;
constexpr int H1   = 4;           // heads layer 1
constexpr int OUTD = 128;
constexpr float SLOPE = 0.2f;
constexpr float BNEPS = 1e-5f;
constexpr int NPART = 32;         // BN partial buffers (contention limiter)

typedef unsigned short u16;
typedef float f32x4 __attribute__((ext_vector_type(4)));
typedef short bf16x8 __attribute__((ext_vector_type(8)));
typedef unsigned short u16x8 __attribute__((ext_vector_type(8)));

__device__ __forceinline__ float bf2f(u16 u) { return __uint_as_float((unsigned)u << 16); }
__device__ __forceinline__ u16 f2bf(float f) {
  unsigned u = __float_as_uint(f);
  unsigned r = u + 0x7FFFu + ((u >> 16) & 1u);  // RNE
  return (u16)(r >> 16);
}

// ---------------- prep: W1/W2 bf16 transpose-pack + degree histogram ----------------
__global__ __launch_bounds__(256) void prep_k(const int* __restrict__ ei,
                                              const float* __restrict__ W1,
                                              const float* __restrict__ W2,
                                              u16* __restrict__ wp1,
                                              u16* __restrict__ wp2,
                                              int* __restrict__ cnt) {
  const int i = blockIdx.x * 256 + threadIdx.x;
  if (i < IN_D * HID) {           // 32768
    const int n = i >> 7, k = i & 127;
    wp1[i] = f2bf(W1[(size_t)k * HID + n]);
  }
  if (i < HID * OUTD) {           // 32768
    const int n = i >> 8, k = i & 255;
    wp2[i] = f2bf(W2[(size_t)k * OUTD + n]);
  }
  if (i < N_ET) {
    const int dst = (i < N_E) ? ei[N_E + i] : (i - N_E);
    atomicAdd(&cnt[dst], 1);
  }
}

// ---------------- scan: 1 block, 1024 thr, shuffle wave-scan (2 barriers) ----------
__global__ __launch_bounds__(1024) void scan_k(const int* __restrict__ cnt,
                                               int* __restrict__ rowptr,
                                               int* __restrict__ wcur) {
  __shared__ int wsum[17];
  const int tid = threadIdx.x, lane = tid & 63, wv = tid >> 6;
  constexpr int CHK = 20;         // 1024*20 = 20480 >= 20000
  const int base = tid * CHK;
  int c[CHK];
  int s = 0;
#pragma unroll
  for (int j = 0; j < CHK; ++j) {
    const int idx = base + j;
    c[j] = (idx < N_N) ? cnt[idx] : 0;
    s += c[j];
  }
  const int own = s;
#pragma unroll
  for (int off = 1; off < 64; off <<= 1) {
    const int v = __shfl_up(s, off, 64);
    if (lane >= off) s += v;
  }
  if (lane == 63) wsum[wv] = s;
  __syncthreads();
  if (tid == 0) {
    int run = 0;
#pragma unroll
    for (int i = 0; i < 16; ++i) { const int t = wsum[i]; wsum[i] = run; run += t; }
    wsum[16] = run;
  }
  __syncthreads();
  int run = wsum[wv] + (s - own);
#pragma unroll
  for (int j = 0; j < CHK; ++j) {
    const int idx = base + j;
    if (idx < N_N) {
      rowptr[idx] = run;
      wcur[idx]   = run;
      run += c[j];
    }
  }
  if (tid == 0) rowptr[N_N] = wsum[16];
}

// ---------------- fused: CSR scatter (blocks >= GB1) + GEMM1 MFMA + alpha1 --------
constexpr int GB1 = N_N / 16;   // 1250 gemm blocks
__global__ __launch_bounds__(256) void sg_k(const float* __restrict__ x,
                                            const u16* __restrict__ wp,     // [256][128]
                                            const float* __restrict__ asrc,
                                            const float* __restrict__ adst,
                                            u16* __restrict__ h,            // [20000][256]
                                            float* __restrict__ as_,        // [20000][4]
                                            float* __restrict__ ad_,
                                            const int* __restrict__ ei,
                                            int* __restrict__ wcur,
                                            int* __restrict__ col) {
  const int tid = threadIdx.x;
  if (blockIdx.x >= GB1) {
    const int i = (blockIdx.x - GB1) * 256 + tid;
    if (i >= N_ET) return;
    int s, dst;
    if (i < N_E) { s = ei[i]; dst = ei[N_E + i]; } else { s = dst = i - N_E; }
    const int pos = atomicAdd(&wcur[dst], 1);
    col[pos] = s;
    return;
  }
  const int wv = tid >> 6, lane = tid & 63;
  const int q = lane >> 4, t = lane & 15;
  const int m0 = blockIdx.x * 16;
  const int n0 = wv * 64;
  f32x4 acc[4] = {};
#pragma unroll
  for (int kb = 0; kb < 4; ++kb) {
    const int k0 = kb * 32 + q * 8;
    const float4 x0 = *(const float4*)(x + (size_t)(m0 + t) * 128 + k0);
    const float4 x1 = *(const float4*)(x + (size_t)(m0 + t) * 128 + k0 + 4);
    bf16x8 a;
    a[0] = (short)f2bf(x0.x); a[1] = (short)f2bf(x0.y);
    a[2] = (short)f2bf(x0.z); a[3] = (short)f2bf(x0.w);
    a[4] = (short)f2bf(x1.x); a[5] = (short)f2bf(x1.y);
    a[6] = (short)f2bf(x1.z); a[7] = (short)f2bf(x1.w);
#pragma unroll
    for (int nt = 0; nt < 4; ++nt) {
      const int n = n0 + nt * 16 + t;
      const bf16x8 b = *(const bf16x8*)(wp + (size_t)n * 128 + k0);
      acc[nt] = __builtin_amdgcn_mfma_f32_16x16x32_bf16(a, b, acc[nt], 0, 0, 0);
    }
  }
  float ps[4] = {0.f, 0.f, 0.f, 0.f}, pd[4] = {0.f, 0.f, 0.f, 0.f};
#pragma unroll
  for (int nt = 0; nt < 4; ++nt) {
    const int coln = n0 + nt * 16 + t;
    const float a_s = asrc[coln], a_d = adst[coln];
#pragma unroll
    for (int r = 0; r < 4; ++r) {
      const float d = acc[nt][r];
      h[(size_t)(m0 + q * 4 + r) * 256 + coln] = f2bf(d);
      ps[r] += d * a_s;
      pd[r] += d * a_d;
    }
  }
#pragma unroll
  for (int off = 1; off < 16; off <<= 1)
#pragma unroll
    for (int r = 0; r < 4; ++r) {
      ps[r] += __shfl_xor(ps[r], off, 64);
      pd[r] += __shfl_xor(pd[r], off, 64);
    }
  if (t == 0) {
#pragma unroll
    for (int r = 0; r < 4; ++r) {
      const int row = m0 + q * 4 + r;
      as_[(size_t)row * 4 + wv] = ps[r];
      ad_[(size_t)row * 4 + wv] = pd[r];
    }
  }
}

// ---------------- agg (both layers): XCD-sharded 64-channel slices -----------------
// Each block: 4 waves = 4 nodes, ONE 64-ch slice (slice = blockIdx & (SLICES-1)).
// With round-robin blockIdx->XCD, slice q lands on XCDs {q mod SLICES} -> per-XCD L2
// working set = 20000*128B = 2.56 MB (fits 4 MB) instead of the whole h (10.2/5.1 MB).
// Wave: 8 parity groups x 8 lanes x 8 ch; 32 edges per 4-load round, 16B/lane loads.
// For HEADS=4 the slice IS the head (64 ch/head) -> scalar as_ gather per pass.
template<int HSTRIDE, int HEADS, int SLICES>
__global__ __launch_bounds__(256) void gat_agg_k(const int* __restrict__ rowptr,
                                                 const int* __restrict__ col,
                                                 const u16* __restrict__ h,
                                                 const float* __restrict__ as_,
                                                 const float* __restrict__ ad_,
                                                 u16* __restrict__ out,
                                                 float* __restrict__ accp) { // [NPART][2*HSTRIDE]
  constexpr int LOGS = (SLICES == 4) ? 2 : 1;
  __shared__ float s_w[4][64];
  __shared__ __align__(16) float st_s[4][64], st_q[4][64];
  const int tid = threadIdx.x;
  const int wv = tid >> 6, lane = tid & 63;
  const int q  = blockIdx.x & (SLICES - 1);
  const int n  = (blockIdx.x >> LOGS) * 4 + wv;
  const int beg = rowptr[n], end = rowptr[n + 1];
  const int eh = lane >> 3;          // 8-way edge parity
  const int cp = lane & 7;           // channel lane within slice
  const int c0 = q * 64 + cp * 8;    // channel base within row
  const float adv = ad_[(size_t)n * HEADS + (HEADS == 4 ? q : 0)];

  float a[8] = {};
  float smh = 0.f;

  for (int j0 = beg; j0 < end; j0 += 64) {
    const int cnt = min(64, end - j0);
    const int j = j0 + lane;
    const int sl = col[(j < end) ? j : beg];

    // prefetch round 0 (32 edges, indices via cross-lane shuffle)
    u16x8 gA[4];
#pragma unroll
    for (int u = 0; u < 4; ++u) {
      const int sv = __shfl(sl, u * 8 + eh, 64);
      gA[u] = *(const u16x8*)(h + (size_t)sv * HSTRIDE + c0);
    }

    // per-edge weight for this slice's head (overlaps with gA in flight)
    float e = as_[(size_t)sl * HEADS + (HEADS == 4 ? q : 0)] + adv;
    e = e > 0.f ? e : SLOPE * e;
    s_w[wv][lane] = (j < end) ? __expf(e) : 0.f;
    // wave-synchronous LDS (same wave wrote it)

    const int rounds = (cnt + 31) >> 5;   // zero-weight padding beyond cnt
    for (int r = 0; r < rounds; ++r) {
      u16x8 gB[4];
      if (r + 1 < rounds) {
        const int nb = (r + 1) * 32;
#pragma unroll
        for (int u = 0; u < 4; ++u) {
          const int sv = __shfl(sl, nb + u * 8 + eh, 64);
          gB[u] = *(const u16x8*)(h + (size_t)sv * HSTRIDE + c0);
        }
      }
      const int rb = r * 32;
#pragma unroll
      for (int u = 0; u < 4; ++u) {
        const float w = s_w[wv][rb + u * 8 + eh];
        smh += w;
#pragma unroll
        for (int k = 0; k < 8; ++k) a[k] = fmaf(w, bf2f(gA[u][k]), a[k]);
      }
      if (r + 1 < rounds) {
#pragma unroll
        for (int u = 0; u < 4; ++u) gA[u] = gB[u];
      }
    }
  }

  // combine 8 parity groups (aggregation is linear)
  smh += __shfl_xor(smh, 8, 64);
  smh += __shfl_xor(smh, 16, 64);
  smh += __shfl_xor(smh, 32, 64);
#pragma unroll
  for (int k = 0; k < 8; ++k) {
    a[k] += __shfl_xor(a[k], 8, 64);
    a[k] += __shfl_xor(a[k], 16, 64);
    a[k] += __shfl_xor(a[k], 32, 64);
  }

  const float rr = 1.f / (smh + 1e-16f);
  float v[8];
#pragma unroll
  for (int k = 0; k < 8; ++k) v[k] = a[k] * rr;

  if (lane < 8) {   // eh==0 lanes own distinct channel chunks
    u16x8 o;
#pragma unroll
    for (int k = 0; k < 8; ++k) o[k] = f2bf(v[k]);
    *(u16x8*)(out + (size_t)n * HSTRIDE + c0) = o;
    float4 s0, s1, q0, q1;
    s0.x = v[0]; s0.y = v[1]; s0.z = v[2]; s0.w = v[3];
    s1.x = v[4]; s1.y = v[5]; s1.z = v[6]; s1.w = v[7];
    q0.x = v[0]*v[0]; q0.y = v[1]*v[1]; q0.z = v[2]*v[2]; q0.w = v[3]*v[3];
    q1.x = v[4]*v[4]; q1.y = v[5]*v[5]; q1.z = v[6]*v[6]; q1.w = v[7]*v[7];
    const int cb = lane * 8;
    *(float4*)(&st_s[wv][cb])     = s0;
    *(float4*)(&st_s[wv][cb + 4]) = s1;
    *(float4*)(&st_q[wv][cb])     = q0;
    *(float4*)(&st_q[wv][cb + 4]) = q1;
  }
  __syncthreads();
  if (tid < 64) {
    const int c = tid;   // slice-local channel
    const float s  = st_s[0][c] + st_s[1][c] + st_s[2][c] + st_s[3][c];
    const float qq = st_q[0][c] + st_q[1][c] + st_q[2][c] + st_q[3][c];
    float* dst = accp + (size_t)(blockIdx.x & (NPART - 1)) * (2 * HSTRIDE);
    atomicAdd(&dst[q * 64 + c], s);
    atomicAdd(&dst[HSTRIDE + q * 64 + c], qq);
  }
}

// ---------------- GEMM2 (MFMA) + BN1 finalize-from-partials + ELU on A + alpha2 ----
__global__ __launch_bounds__(256) void gemm2_mfma_k(const u16* __restrict__ hin,
                                                    const float* __restrict__ accp, // [32][512]
                                                    const float* __restrict__ g1,
                                                    const float* __restrict__ b1,
                                                    const u16* __restrict__ wp,   // [128][256]
                                                    const float* __restrict__ asrc,
                                                    const float* __restrict__ adst,
                                                    u16* __restrict__ h2,
                                                    float* __restrict__ as_,
                                                    float* __restrict__ ad_) {
  __shared__ float scsh[512];
  __shared__ float red[2][32][2];
  const int tid = threadIdx.x;
  {  // BN1 finalize: sum 32 partials per channel
    float s = 0.f, q = 0.f;
#pragma unroll
    for (int p = 0; p < NPART; ++p) {
      s += accp[(size_t)p * 512 + tid];
      q += accp[(size_t)p * 512 + 256 + tid];
    }
    const float mean = s * (1.f / N_N);
    const float var  = q * (1.f / N_N) - mean * mean;
    const float inv  = rsqrtf(var + BNEPS);
    const float sc   = g1[tid] * inv;
    scsh[tid]       = sc;
    scsh[256 + tid] = b1[tid] - mean * sc;
  }
  __syncthreads();
  const int wv = tid >> 6, lane = tid & 63;
  const int q = lane >> 4, t = lane & 15;
  const int mh = wv >> 1, nh = wv & 1;
  const int m0 = blockIdx.x * 32 + mh * 16;
  const int n0 = nh * 64;
  f32x4 acc[4] = {};
#pragma unroll
  for (int kb = 0; kb < 8; ++kb) {
    const int k0 = kb * 32 + q * 8;
    const ushort4 u0 = *(const ushort4*)(hin + (size_t)(m0 + t) * 256 + k0);
    const ushort4 u1 = *(const ushort4*)(hin + (size_t)(m0 + t) * 256 + k0 + 4);
    const float4 sc0 = *(const float4*)(scsh + k0);
    const float4 sc1 = *(const float4*)(scsh + k0 + 4);
    const float4 sh0 = *(const float4*)(scsh + 256 + k0);
    const float4 sh1 = *(const float4*)(scsh + 256 + k0 + 4);
    float v[8];
    v[0] = bf2f(u0.x) * sc0.x + sh0.x;
    v[1] = bf2f(u0.y) * sc0.y + sh0.y;
    v[2] = bf2f(u0.z) * sc0.z + sh0.z;
    v[3] = bf2f(u0.w) * sc0.w + sh0.w;
    v[4] = bf2f(u1.x) * sc1.x + sh1.x;
    v[5] = bf2f(u1.y) * sc1.y + sh1.y;
    v[6] = bf2f(u1.z) * sc1.z + sh1.z;
    v[7] = bf2f(u1.w) * sc1.w + sh1.w;
    bf16x8 a;
#pragma unroll
    for (int j = 0; j < 8; ++j) {
      const float e = v[j] > 0.f ? v[j] : __expf(v[j]) - 1.f;
      a[j] = (short)f2bf(e);
    }
#pragma unroll
    for (int nt = 0; nt < 4; ++nt) {
      const int n = n0 + nt * 16 + t;
      const bf16x8 b = *(const bf16x8*)(wp + (size_t)n * 256 + k0);
      acc[nt] = __builtin_amdgcn_mfma_f32_16x16x32_bf16(a, b, acc[nt], 0, 0, 0);
    }
  }
  float ps[4] = {0.f, 0.f, 0.f, 0.f}, pd[4] = {0.f, 0.f, 0.f, 0.f};
#pragma unroll
  for (int nt = 0; nt < 4; ++nt) {
    const int coln = n0 + nt * 16 + t;
    const float a_s = asrc[coln], a_d = adst[coln];
#pragma unroll
    for (int r = 0; r < 4; ++r) {
      const float d = acc[nt][r];
      h2[(size_t)(m0 + q * 4 + r) * 128 + coln] = f2bf(d);
      ps[r] += d * a_s;
      pd[r] += d * a_d;
    }
  }
#pragma unroll
  for (int off = 1; off < 16; off <<= 1)
#pragma unroll
    for (int r = 0; r < 4; ++r) {
      ps[r] += __shfl_xor(ps[r], off, 64);
      pd[r] += __shfl_xor(pd[r], off, 64);
    }
  if (t == 0) {
#pragma unroll
    for (int r = 0; r < 4; ++r) {
      red[0][mh * 16 + q * 4 + r][nh] = ps[r];
      red[1][mh * 16 + q * 4 + r][nh] = pd[r];
    }
  }
  __syncthreads();
  if (tid < 32) {
    as_[(size_t)blockIdx.x * 32 + tid] = red[0][tid][0] + red[0][tid][1];
    ad_[(size_t)blockIdx.x * 32 + tid] = red[1][tid][0] + red[1][tid][1];
  }
}

// ---------------- BN2 finalize-from-partials + apply, bf16 -> fp32 out -------------
__global__ __launch_bounds__(256) void apply_k(const u16* __restrict__ X,
                                               const float* __restrict__ accp, // [32][256]
                                               const float* __restrict__ gamma,
                                               const float* __restrict__ beta,
                                               float* __restrict__ Y) {
  __shared__ float s_sc[128], s_sh[128];
  const int tid = threadIdx.x;
  if (tid < 128) {
    float s = 0.f, q = 0.f;
#pragma unroll
    for (int p = 0; p < NPART; ++p) {
      s += accp[(size_t)p * 256 + tid];
      q += accp[(size_t)p * 256 + 128 + tid];
    }
    const float mean = s * (1.f / N_N);
    const float var  = q * (1.f / N_N) - mean * mean;
    const float inv  = rsqrtf(var + BNEPS);
    const float sc   = gamma[tid] * inv;
    s_sc[tid] = sc;
    s_sh[tid] = beta[tid] - mean * sc;
  }
  __syncthreads();
  constexpr size_t TOT = (size_t)N_N * OUTD;
  for (size_t i = ((size_t)blockIdx.x * 256 + tid) * 4; i < TOT;
       i += (size_t)gridDim.x * 256 * 4) {
    const ushort4 u = *(const ushort4*)(X + i);
    const int c = (int)(i & 127);
    float4 o;
    o.x = bf2f(u.x) * s_sc[c]     + s_sh[c];
    o.y = bf2f(u.y) * s_sc[c + 1] + s_sh[c + 1];
    o.z = bf2f(u.z) * s_sc[c + 2] + s_sh[c + 2];
    o.w = bf2f(u.w) * s_sc[c + 3] + s_sh[c + 3];
    *(float4*)(Y + i) = o;
  }
}

// ---------------- workspace layout (4-byte element offsets) ----------------
constexpr size_t OFF_WP1  = 0;                                   // bf16 256*128
constexpr size_t OFF_WP2  = OFF_WP1  + (size_t)IN_D * HID / 2;
constexpr size_t OFF_H1   = OFF_WP2  + (size_t)HID * OUTD / 2;   // bf16 N_N*HID
constexpr size_t OFF_OUT1 = OFF_H1   + (size_t)N_N * HID / 2;
constexpr size_t OFF_H2   = OFF_OUT1 + (size_t)N_N * HID / 2;    // bf16 N_N*OUTD
constexpr size_t OFF_OUT2 = OFF_H2   + (size_t)N_N * OUTD / 2;
constexpr size_t OFF_AS1  = OFF_OUT2 + (size_t)N_N * OUTD / 2;   // fp32 N_N*4
constexpr size_t OFF_AD1  = OFF_AS1  + (size_t)N_N * H1;
constexpr size_t OFF_AS2  = OFF_AD1  + (size_t)N_N * H1;         // fp32 N_N
constexpr size_t OFF_AD2  = OFF_AS2  + (size_t)N_N;
constexpr size_t OFF_ROWP = OFF_AD2  + (size_t)N_N;              // int N_N+1
constexpr size_t OFF_COL  = OFF_ROWP + (size_t)(N_N + 1);        // int N_ET
constexpr size_t OFF_WCUR = OFF_COL  + (size_t)N_ET;             // int N_N
// zeroed region (one memset): cnt + acc partials
constexpr size_t OFF_CNT  = OFF_WCUR + (size_t)N_N;              // int N_N
constexpr size_t OFF_ACC1 = OFF_CNT  + (size_t)N_N;              // 32*512 fp32
constexpr size_t OFF_ACC2 = OFF_ACC1 + (size_t)NPART * 512;      // 32*256 fp32
constexpr size_t OFF_ZEND = OFF_ACC2 + (size_t)NPART * 256;

extern "C" void kernel_launch(void* const* d_in, const int* in_sizes, int n_in,
                              void* d_out, int out_size, void* d_ws, size_t ws_size,
                              hipStream_t stream) {
  const float* x      = (const float*)d_in[0];
  const int*   ei     = (const int*)d_in[1];
  const float* W1     = (const float*)d_in[2];
  const float* asrc1  = (const float*)d_in[3];
  const float* adst1  = (const float*)d_in[4];
  // d_in[5] = bias1 (cancels under BN)
  const float* g1     = (const float*)d_in[6];
  const float* b1     = (const float*)d_in[7];
  const float* W2     = (const float*)d_in[8];
  const float* asrc2  = (const float*)d_in[9];
  const float* adst2  = (const float*)d_in[10];
  // d_in[11] = bias2 (cancels under BN)
  const float* g2     = (const float*)d_in[12];
  const float* b2     = (const float*)d_in[13];

  float* ws = (float*)d_ws;
  u16*   wp1   = (u16*)(ws + OFF_WP1);
  u16*   wp2   = (u16*)(ws + OFF_WP2);
  u16*   h1    = (u16*)(ws + OFF_H1);
  u16*   out1  = (u16*)(ws + OFF_OUT1);
  u16*   h2    = (u16*)(ws + OFF_H2);
  u16*   out2  = (u16*)(ws + OFF_OUT2);
  float* as1   = ws + OFF_AS1;
  float* ad1   = ws + OFF_AD1;
  float* as2   = ws + OFF_AS2;
  float* ad2   = ws + OFF_AD2;
  int*   rowp  = (int*)(ws + OFF_ROWP);
  int*   col   = (int*)(ws + OFF_COL);
  int*   wcur  = (int*)(ws + OFF_WCUR);
  int*   cnt   = (int*)(ws + OFF_CNT);
  float* acc1p = ws + OFF_ACC1;
  float* acc2p = ws + OFF_ACC2;
  float* outf  = (float*)d_out;

  // zero: cnt + acc partials (contiguous, ~178 KB)
  hipMemsetAsync(cnt, 0, (OFF_ZEND - OFF_CNT) * sizeof(float), stream);

  const int eb = (N_ET + 255) / 256;   // 1329
  // 1. W packs + degree histogram
  prep_k<<<eb, 256, 0, stream>>>(ei, W1, W2, wp1, wp2, cnt);
  // 2. exclusive scan -> rowptr/wcur
  scan_k<<<1, 1024, 0, stream>>>(cnt, rowp, wcur);
  // 3. CSR scatter + GEMM1(+alpha1) fused
  sg_k<<<GB1 + eb, 256, 0, stream>>>(x, wp1, asrc1, adst1, h1, as1, ad1, ei, wcur, col);
  // 4. layer-1 edge softmax + aggregate + BN1 stats (4 XCD-sharded 64-ch slices)
  gat_agg_k<HID, H1, 4><<<(N_N / 4) * 4, 256, 0, stream>>>(rowp, col, h1, as1, ad1, out1, acc1p);
  // 5. GEMM2 (BN1 finalize + BN1/ELU on A, fused alpha2)
  gemm2_mfma_k<<<N_N / 32, 256, 0, stream>>>(out1, acc1p, g1, b1, wp2, asrc2, adst2, h2, as2, ad2);
  // 6. layer-2 edge softmax + aggregate + BN2 stats (2 XCD-sharded 64-ch slices)
  gat_agg_k<OUTD, 1, 2><<<(N_N / 4) * 2, 256, 0, stream>>>(rowp, col, h2, as2, ad2, out2, acc2p);
  // 7. BN2 finalize + apply -> fp32 output
  apply_k<<<512, 256, 0, stream>>>(out2, acc2p, g2, b2, outf);
}

// Round 8
// 234.852 us; speedup vs baseline: 1.1022x; 1.1022x over previous
//
#include <hip/hip_runtime.h>
#include <type_traits>

constexpr int N_N  = 20000;
constexpr int N_E  = 320000;
constexpr int N_ET = N_E + N_N;   // 340000 (self-loops appended)
constexpr int IN_D = 128;
constexpr int HID  = 256;
constexpr int H1   = 4;           // heads layer 1
constexpr int OUTD = 128;
constexpr float SLOPE = 0.2f;
constexpr float BNEPS = 1e-5f;
constexpr int NPART = 32;         // BN partial buffers (contention limiter)

typedef unsigned short u16;
typedef float f32x4 __attribute__((ext_vector_type(4)));
typedef short bf16x8 __attribute__((ext_vector_type(8)));
typedef unsigned short u16x8 __attribute__((ext_vector_type(8)));

__device__ __forceinline__ float bf2f(u16 u) { return __uint_as_float((unsigned)u << 16); }
__device__ __forceinline__ u16 f2bf(float f) {
  unsigned u = __float_as_uint(f);
  unsigned r = u + 0x7FFFu + ((u >> 16) & 1u);  // RNE
  return (u16)(r >> 16);
}

// ---------------- prep: W1/W2 bf16 transpose-pack + degree histogram ----------------
__global__ __launch_bounds__(256) void prep_k(const int* __restrict__ ei,
                                              const float* __restrict__ W1,
                                              const float* __restrict__ W2,
                                              u16* __restrict__ wp1,
                                              u16* __restrict__ wp2,
                                              int* __restrict__ cnt) {
  const int i = blockIdx.x * 256 + threadIdx.x;
  if (i < IN_D * HID) {           // 32768
    const int n = i >> 7, k = i & 127;
    wp1[i] = f2bf(W1[(size_t)k * HID + n]);
  }
  if (i < HID * OUTD) {           // 32768
    const int n = i >> 8, k = i & 255;
    wp2[i] = f2bf(W2[(size_t)k * OUTD + n]);
  }
  if (i < N_ET) {
    const int dst = (i < N_E) ? ei[N_E + i] : (i - N_E);
    atomicAdd(&cnt[dst], 1);
  }
}

// ---------------- scan: 1 block, 1024 thr, shuffle wave-scan (2 barriers) ----------
__global__ __launch_bounds__(1024) void scan_k(const int* __restrict__ cnt,
                                               int* __restrict__ rowptr,
                                               int* __restrict__ wcur) {
  __shared__ int wsum[17];
  const int tid = threadIdx.x, lane = tid & 63, wv = tid >> 6;
  constexpr int CHK = 20;         // 1024*20 = 20480 >= 20000
  const int base = tid * CHK;
  int c[CHK];
  int s = 0;
#pragma unroll
  for (int j = 0; j < CHK; ++j) {
    const int idx = base + j;
    c[j] = (idx < N_N) ? cnt[idx] : 0;
    s += c[j];
  }
  const int own = s;
#pragma unroll
  for (int off = 1; off < 64; off <<= 1) {
    const int v = __shfl_up(s, off, 64);
    if (lane >= off) s += v;
  }
  if (lane == 63) wsum[wv] = s;
  __syncthreads();
  if (tid == 0) {
    int run = 0;
#pragma unroll
    for (int i = 0; i < 16; ++i) { const int t = wsum[i]; wsum[i] = run; run += t; }
    wsum[16] = run;
  }
  __syncthreads();
  int run = wsum[wv] + (s - own);
#pragma unroll
  for (int j = 0; j < CHK; ++j) {
    const int idx = base + j;
    if (idx < N_N) {
      rowptr[idx] = run;
      wcur[idx]   = run;
      run += c[j];
    }
  }
  if (tid == 0) rowptr[N_N] = wsum[16];
}

// ---------------- fused: CSR scatter (blocks >= GB1) + GEMM1 MFMA + alpha1 --------
constexpr int GB1 = N_N / 16;   // 1250 gemm blocks
__global__ __launch_bounds__(256) void sg_k(const float* __restrict__ x,
                                            const u16* __restrict__ wp,     // [256][128]
                                            const float* __restrict__ asrc,
                                            const float* __restrict__ adst,
                                            u16* __restrict__ h,            // [20000][256]
                                            float* __restrict__ as_,        // [20000][4]
                                            float* __restrict__ ad_,
                                            const int* __restrict__ ei,
                                            int* __restrict__ wcur,
                                            int* __restrict__ col) {
  const int tid = threadIdx.x;
  if (blockIdx.x >= GB1) {
    const int i = (blockIdx.x - GB1) * 256 + tid;
    if (i >= N_ET) return;
    int s, dst;
    if (i < N_E) { s = ei[i]; dst = ei[N_E + i]; } else { s = dst = i - N_E; }
    const int pos = atomicAdd(&wcur[dst], 1);
    col[pos] = s;
    return;
  }
  const int wv = tid >> 6, lane = tid & 63;
  const int q = lane >> 4, t = lane & 15;
  const int m0 = blockIdx.x * 16;
  const int n0 = wv * 64;
  f32x4 acc[4] = {};
#pragma unroll
  for (int kb = 0; kb < 4; ++kb) {
    const int k0 = kb * 32 + q * 8;
    const float4 x0 = *(const float4*)(x + (size_t)(m0 + t) * 128 + k0);
    const float4 x1 = *(const float4*)(x + (size_t)(m0 + t) * 128 + k0 + 4);
    bf16x8 a;
    a[0] = (short)f2bf(x0.x); a[1] = (short)f2bf(x0.y);
    a[2] = (short)f2bf(x0.z); a[3] = (short)f2bf(x0.w);
    a[4] = (short)f2bf(x1.x); a[5] = (short)f2bf(x1.y);
    a[6] = (short)f2bf(x1.z); a[7] = (short)f2bf(x1.w);
#pragma unroll
    for (int nt = 0; nt < 4; ++nt) {
      const int n = n0 + nt * 16 + t;
      const bf16x8 b = *(const bf16x8*)(wp + (size_t)n * 128 + k0);
      acc[nt] = __builtin_amdgcn_mfma_f32_16x16x32_bf16(a, b, acc[nt], 0, 0, 0);
    }
  }
  float ps[4] = {0.f, 0.f, 0.f, 0.f}, pd[4] = {0.f, 0.f, 0.f, 0.f};
#pragma unroll
  for (int nt = 0; nt < 4; ++nt) {
    const int coln = n0 + nt * 16 + t;
    const float a_s = asrc[coln], a_d = adst[coln];
#pragma unroll
    for (int r = 0; r < 4; ++r) {
      const float d = acc[nt][r];
      h[(size_t)(m0 + q * 4 + r) * 256 + coln] = f2bf(d);
      ps[r] += d * a_s;
      pd[r] += d * a_d;
    }
  }
#pragma unroll
  for (int off = 1; off < 16; off <<= 1)
#pragma unroll
    for (int r = 0; r < 4; ++r) {
      ps[r] += __shfl_xor(ps[r], off, 64);
      pd[r] += __shfl_xor(pd[r], off, 64);
    }
  if (t == 0) {
#pragma unroll
    for (int r = 0; r < 4; ++r) {
      const int row = m0 + q * 4 + r;
      as_[(size_t)row * 4 + wv] = ps[r];
      ad_[(size_t)row * 4 + wv] = pd[r];
    }
  }
}

// ---------------- edge-weight materialization: w[pos] = exp(leaky(as+ad)) ----------
// One wave per node; coalesced col read, random as_ gather (L2-resident), stream write.
template<int HEADS>
__global__ __launch_bounds__(256) void wgen_k(const int* __restrict__ rowptr,
                                              const int* __restrict__ col,
                                              const float* __restrict__ as_,
                                              const float* __restrict__ ad_,
                                              float* __restrict__ w) {
  const int tid = threadIdx.x;
  const int wv = tid >> 6, lane = tid & 63;
  const int n = blockIdx.x * 4 + wv;
  const int beg = rowptr[n], end = rowptr[n + 1];
  if (HEADS == 4) {
    const float4 adv = *(const float4*)(ad_ + (size_t)n * 4);
    for (int j = beg + lane; j < end; j += 64) {
      const int sl = col[j];
      const float4 av = *(const float4*)(as_ + (size_t)sl * 4);
      float e0 = av.x + adv.x; e0 = e0 > 0.f ? e0 : SLOPE * e0;
      float e1 = av.y + adv.y; e1 = e1 > 0.f ? e1 : SLOPE * e1;
      float e2 = av.z + adv.z; e2 = e2 > 0.f ? e2 : SLOPE * e2;
      float e3 = av.w + adv.w; e3 = e3 > 0.f ? e3 : SLOPE * e3;
      float4 o;
      o.x = __expf(e0); o.y = __expf(e1); o.z = __expf(e2); o.w = __expf(e3);
      *(float4*)(w + (size_t)j * 4) = o;
    }
  } else {
    const float adv = ad_[n];
    for (int j = beg + lane; j < end; j += 64) {
      const int sl = col[j];
      float e = as_[sl] + adv;
      e = e > 0.f ? e : SLOPE * e;
      w[j] = __expf(e);
    }
  }
}

// ---------------- agg layer 1: 1 wave per node, 16B/lane loads, 2-edge parity ------
// Weights pre-materialized (streamed float4) — no random as_ gather, no exp here.
__global__ __launch_bounds__(256) void gat_agg1_k(const int* __restrict__ rowptr,
                                                  const int* __restrict__ col,
                                                  const u16* __restrict__ h,
                                                  const float* __restrict__ w1,
                                                  u16* __restrict__ out,
                                                  float* __restrict__ accp) {  // [32][512]
  __shared__ __align__(16) float s_w[4][64][4];
  __shared__ __align__(16) float st_s[4][256], st_q[4][256];
  const int tid = threadIdx.x;
  const int wv = tid >> 6, lane = tid & 63;
  const int n = blockIdx.x * 4 + wv;
  const int beg = rowptr[n], end = rowptr[n + 1];
  const int eh = lane >> 5;         // edge parity of this lane
  const int cp = lane & 31;
  const int c0 = cp * 8;            // 8-channel base
  const int hl = cp >> 3;           // head of these channels (64 ch per head)

  float a[8] = {};
  float smh = 0.f;

  for (int j0 = beg; j0 < end; j0 += 64) {
    const int cnt = min(64, end - j0);
    const int j = j0 + lane;
    const bool valid = j < end;
    const int js = valid ? j : beg;
    const int sl = col[js];

    // issue batch-0 row loads immediately (indices via cross-lane shuffle)
    u16x8 gA[4];
#pragma unroll
    for (int u = 0; u < 4; ++u) {
      const int sv = __shfl(sl, 2 * u + eh, 64);
      gA[u] = *(const u16x8*)(h + (size_t)sv * 256 + c0);
    }

    // streamed per-edge weights (overlaps with gA in flight)
    const float4 wl = *(const float4*)(w1 + (size_t)js * 4);
    float4 w4;
    w4.x = valid ? wl.x : 0.f;
    w4.y = valid ? wl.y : 0.f;
    w4.z = valid ? wl.z : 0.f;
    w4.w = valid ? wl.w : 0.f;
    *(float4*)(&s_w[wv][lane][0]) = w4;
    // wave-synchronous LDS (same wave wrote it)

    const int rounds = (cnt + 7) >> 3;   // zero-weight padding beyond cnt
    for (int r = 0; r < rounds; ++r) {
      u16x8 gB[4];
      if (r + 1 < rounds) {
        const int nb = (r + 1) * 8;
#pragma unroll
        for (int u = 0; u < 4; ++u) {
          const int sv = __shfl(sl, nb + 2 * u + eh, 64);
          gB[u] = *(const u16x8*)(h + (size_t)sv * 256 + c0);
        }
      }
      const int rb = r * 8;
#pragma unroll
      for (int u = 0; u < 4; ++u) {
        const float w = s_w[wv][rb + 2 * u + eh][hl];
        smh += w;
#pragma unroll
        for (int k = 0; k < 8; ++k) a[k] = fmaf(w, bf2f(gA[u][k]), a[k]);
      }
      if (r + 1 < rounds) {
#pragma unroll
        for (int u = 0; u < 4; ++u) gA[u] = gB[u];
      }
    }
  }

  // combine edge-parity halves (aggregation is linear)
  smh += __shfl_xor(smh, 32, 64);
#pragma unroll
  for (int k = 0; k < 8; ++k) a[k] += __shfl_xor(a[k], 32, 64);

  const float rr = 1.f / (smh + 1e-16f);
  float v[8];
#pragma unroll
  for (int k = 0; k < 8; ++k) v[k] = a[k] * rr;

  if (lane < 32) {
    u16x8 o;
#pragma unroll
    for (int k = 0; k < 8; ++k) o[k] = f2bf(v[k]);
    *(u16x8*)(out + (size_t)n * 256 + c0) = o;
    float4 s0, s1, q0, q1;
    s0.x = v[0]; s0.y = v[1]; s0.z = v[2]; s0.w = v[3];
    s1.x = v[4]; s1.y = v[5]; s1.z = v[6]; s1.w = v[7];
    q0.x = v[0]*v[0]; q0.y = v[1]*v[1]; q0.z = v[2]*v[2]; q0.w = v[3]*v[3];
    q1.x = v[4]*v[4]; q1.y = v[5]*v[5]; q1.z = v[6]*v[6]; q1.w = v[7]*v[7];
    *(float4*)(&st_s[wv][c0])     = s0;
    *(float4*)(&st_s[wv][c0 + 4]) = s1;
    *(float4*)(&st_q[wv][c0])     = q0;
    *(float4*)(&st_q[wv][c0 + 4]) = q1;
  }
  __syncthreads();
  {
    const int c = tid;   // 256 channels
    const float s = st_s[0][c] + st_s[1][c] + st_s[2][c] + st_s[3][c];
    const float q = st_q[0][c] + st_q[1][c] + st_q[2][c] + st_q[3][c];
    float* dst = accp + (size_t)(blockIdx.x & (NPART - 1)) * 512;
    atomicAdd(&dst[c], s);
    atomicAdd(&dst[256 + c], q);
  }
}

// ---------------- agg layer 2: 1 wave per node, 16B/lane loads, 4-edge parity ------
// Weights pre-materialized (streamed scalar) — no random as_ gather, no exp here.
__global__ __launch_bounds__(256) void gat_agg2_k(const int* __restrict__ rowptr,
                                                  const int* __restrict__ col,
                                                  const u16* __restrict__ h,
                                                  const float* __restrict__ w2,
                                                  u16* __restrict__ out,
                                                  float* __restrict__ accp) {  // [32][256]
  __shared__ float s_w[4][64];
  __shared__ __align__(16) float st_s[4][128], st_q[4][128];
  const int tid = threadIdx.x;
  const int wv = tid >> 6, lane = tid & 63;
  const int n = blockIdx.x * 4 + wv;
  const int beg = rowptr[n], end = rowptr[n + 1];
  const int eh = lane >> 4;          // 4-way edge parity
  const int cp = lane & 15;
  const int c0 = cp * 8;             // 8-channel base within 128

  float a[8] = {};
  float smh = 0.f;

  for (int j0 = beg; j0 < end; j0 += 64) {
    const int cnt = min(64, end - j0);
    const int j = j0 + lane;
    const bool valid = j < end;
    const int js = valid ? j : beg;
    const int sl = col[js];

    const int rounds = (cnt + 15) >> 4;   // 16 edges per round
    u16x8 gA[4];
#pragma unroll
    for (int u = 0; u < 4; ++u) {
      const int sv = __shfl(sl, 4 * u + eh, 64);
      gA[u] = *(const u16x8*)(h + (size_t)sv * 128 + c0);
    }

    const float wl = w2[js];
    s_w[wv][lane] = valid ? wl : 0.f;
    // wave-synchronous LDS (same wave wrote it)

    for (int r = 0; r < rounds; ++r) {
      u16x8 gB[4];
      if (r + 1 < rounds) {
        const int nb = (r + 1) * 16;
#pragma unroll
        for (int u = 0; u < 4; ++u) {
          const int sv = __shfl(sl, nb + 4 * u + eh, 64);
          gB[u] = *(const u16x8*)(h + (size_t)sv * 128 + c0);
        }
      }
      const int rb = r * 16;
#pragma unroll
      for (int u = 0; u < 4; ++u) {
        const float w = s_w[wv][rb + 4 * u + eh];
        smh += w;
#pragma unroll
        for (int k = 0; k < 8; ++k) a[k] = fmaf(w, bf2f(gA[u][k]), a[k]);
      }
      if (r + 1 < rounds) {
#pragma unroll
        for (int u = 0; u < 4; ++u) gA[u] = gB[u];
      }
    }
  }

  // combine 4 parity groups (aggregation is linear)
  smh += __shfl_xor(smh, 16, 64);
  smh += __shfl_xor(smh, 32, 64);
#pragma unroll
  for (int k = 0; k < 8; ++k) {
    a[k] += __shfl_xor(a[k], 16, 64);
    a[k] += __shfl_xor(a[k], 32, 64);
  }

  const float rr = 1.f / (smh + 1e-16f);
  float v[8];
#pragma unroll
  for (int k = 0; k < 8; ++k) v[k] = a[k] * rr;

  if (lane < 16) {
    u16x8 o;
#pragma unroll
    for (int k = 0; k < 8; ++k) o[k] = f2bf(v[k]);
    *(u16x8*)(out + (size_t)n * 128 + c0) = o;
    float4 s0, s1, q0, q1;
    s0.x = v[0]; s0.y = v[1]; s0.z = v[2]; s0.w = v[3];
    s1.x = v[4]; s1.y = v[5]; s1.z = v[6]; s1.w = v[7];
    q0.x = v[0]*v[0]; q0.y = v[1]*v[1]; q0.z = v[2]*v[2]; q0.w = v[3]*v[3];
    q1.x = v[4]*v[4]; q1.y = v[5]*v[5]; q1.z = v[6]*v[6]; q1.w = v[7]*v[7];
    *(float4*)(&st_s[wv][c0])     = s0;
    *(float4*)(&st_s[wv][c0 + 4]) = s1;
    *(float4*)(&st_q[wv][c0])     = q0;
    *(float4*)(&st_q[wv][c0 + 4]) = q1;
  }
  __syncthreads();
  if (tid < 128) {
    const int c = tid;
    const float s = st_s[0][c] + st_s[1][c] + st_s[2][c] + st_s[3][c];
    const float q = st_q[0][c] + st_q[1][c] + st_q[2][c] + st_q[3][c];
    float* dst = accp + (size_t)(blockIdx.x & (NPART - 1)) * 256;
    atomicAdd(&dst[c], s);
    atomicAdd(&dst[128 + c], q);
  }
}

// ---------------- GEMM2 (MFMA) + BN1 finalize-from-partials + ELU on A + alpha2 ----
__global__ __launch_bounds__(256) void gemm2_mfma_k(const u16* __restrict__ hin,
                                                    const float* __restrict__ accp, // [32][512]
                                                    const float* __restrict__ g1,
                                                    const float* __restrict__ b1,
                                                    const u16* __restrict__ wp,   // [128][256]
                                                    const float* __restrict__ asrc,
                                                    const float* __restrict__ adst,
                                                    u16* __restrict__ h2,
                                                    float* __restrict__ as_,
                                                    float* __restrict__ ad_) {
  __shared__ float scsh[512];
  __shared__ float red[2][32][2];
  const int tid = threadIdx.x;
  {  // BN1 finalize: sum 32 partials per channel
    float s = 0.f, q = 0.f;
#pragma unroll
    for (int p = 0; p < NPART; ++p) {
      s += accp[(size_t)p * 512 + tid];
      q += accp[(size_t)p * 512 + 256 + tid];
    }
    const float mean = s * (1.f / N_N);
    const float var  = q * (1.f / N_N) - mean * mean;
    const float inv  = rsqrtf(var + BNEPS);
    const float sc   = g1[tid] * inv;
    scsh[tid]       = sc;
    scsh[256 + tid] = b1[tid] - mean * sc;
  }
  __syncthreads();
  const int wv = tid >> 6, lane = tid & 63;
  const int q = lane >> 4, t = lane & 15;
  const int mh = wv >> 1, nh = wv & 1;
  const int m0 = blockIdx.x * 32 + mh * 16;
  const int n0 = nh * 64;
  f32x4 acc[4] = {};
#pragma unroll
  for (int kb = 0; kb < 8; ++kb) {
    const int k0 = kb * 32 + q * 8;
    const ushort4 u0 = *(const ushort4*)(hin + (size_t)(m0 + t) * 256 + k0);
    const ushort4 u1 = *(const ushort4*)(hin + (size_t)(m0 + t) * 256 + k0 + 4);
    const float4 sc0 = *(const float4*)(scsh + k0);
    const float4 sc1 = *(const float4*)(scsh + k0 + 4);
    const float4 sh0 = *(const float4*)(scsh + 256 + k0);
    const float4 sh1 = *(const float4*)(scsh + 256 + k0 + 4);
    float v[8];
    v[0] = bf2f(u0.x) * sc0.x + sh0.x;
    v[1] = bf2f(u0.y) * sc0.y + sh0.y;
    v[2] = bf2f(u0.z) * sc0.z + sh0.z;
    v[3] = bf2f(u0.w) * sc0.w + sh0.w;
    v[4] = bf2f(u1.x) * sc1.x + sh1.x;
    v[5] = bf2f(u1.y) * sc1.y + sh1.y;
    v[6] = bf2f(u1.z) * sc1.z + sh1.z;
    v[7] = bf2f(u1.w) * sc1.w + sh1.w;
    bf16x8 a;
#pragma unroll
    for (int j = 0; j < 8; ++j) {
      const float e = v[j] > 0.f ? v[j] : __expf(v[j]) - 1.f;
      a[j] = (short)f2bf(e);
    }
#pragma unroll
    for (int nt = 0; nt < 4; ++nt) {
      const int n = n0 + nt * 16 + t;
      const bf16x8 b = *(const bf16x8*)(wp + (size_t)n * 256 + k0);
      acc[nt] = __builtin_amdgcn_mfma_f32_16x16x32_bf16(a, b, acc[nt], 0, 0, 0);
    }
  }
  float ps[4] = {0.f, 0.f, 0.f, 0.f}, pd[4] = {0.f, 0.f, 0.f, 0.f};
#pragma unroll
  for (int nt = 0; nt < 4; ++nt) {
    const int coln = n0 + nt * 16 + t;
    const float a_s = asrc[coln], a_d = adst[coln];
#pragma unroll
    for (int r = 0; r < 4; ++r) {
      const float d = acc[nt][r];
      h2[(size_t)(m0 + q * 4 + r) * 128 + coln] = f2bf(d);
      ps[r] += d * a_s;
      pd[r] += d * a_d;
    }
  }
#pragma unroll
  for (int off = 1; off < 16; off <<= 1)
#pragma unroll
    for (int r = 0; r < 4; ++r) {
      ps[r] += __shfl_xor(ps[r], off, 64);
      pd[r] += __shfl_xor(pd[r], off, 64);
    }
  if (t == 0) {
#pragma unroll
    for (int r = 0; r < 4; ++r) {
      red[0][mh * 16 + q * 4 + r][nh] = ps[r];
      red[1][mh * 16 + q * 4 + r][nh] = pd[r];
    }
  }
  __syncthreads();
  if (tid < 32) {
    as_[(size_t)blockIdx.x * 32 + tid] = red[0][tid][0] + red[0][tid][1];
    ad_[(size_t)blockIdx.x * 32 + tid] = red[1][tid][0] + red[1][tid][1];
  }
}

// ---------------- BN2 finalize-from-partials + apply, bf16 -> fp32 out -------------
__global__ __launch_bounds__(256) void apply_k(const u16* __restrict__ X,
                                               const float* __restrict__ accp, // [32][256]
                                               const float* __restrict__ gamma,
                                               const float* __restrict__ beta,
                                               float* __restrict__ Y) {
  __shared__ float s_sc[128], s_sh[128];
  const int tid = threadIdx.x;
  if (tid < 128) {
    float s = 0.f, q = 0.f;
#pragma unroll
    for (int p = 0; p < NPART; ++p) {
      s += accp[(size_t)p * 256 + tid];
      q += accp[(size_t)p * 256 + 128 + tid];
    }
    const float mean = s * (1.f / N_N);
    const float var  = q * (1.f / N_N) - mean * mean;
    const float inv  = rsqrtf(var + BNEPS);
    const float sc   = gamma[tid] * inv;
    s_sc[tid] = sc;
    s_sh[tid] = beta[tid] - mean * sc;
  }
  __syncthreads();
  constexpr size_t TOT = (size_t)N_N * OUTD;
  for (size_t i = ((size_t)blockIdx.x * 256 + tid) * 4; i < TOT;
       i += (size_t)gridDim.x * 256 * 4) {
    const ushort4 u = *(const ushort4*)(X + i);
    const int c = (int)(i & 127);
    float4 o;
    o.x = bf2f(u.x) * s_sc[c]     + s_sh[c];
    o.y = bf2f(u.y) * s_sc[c + 1] + s_sh[c + 1];
    o.z = bf2f(u.z) * s_sc[c + 2] + s_sh[c + 2];
    o.w = bf2f(u.w) * s_sc[c + 3] + s_sh[c + 3];
    *(float4*)(Y + i) = o;
  }
}

// ---------------- workspace layout (4-byte element offsets) ----------------
constexpr size_t OFF_WP1  = 0;                                   // bf16 256*128
constexpr size_t OFF_WP2  = OFF_WP1  + (size_t)IN_D * HID / 2;
constexpr size_t OFF_H1   = OFF_WP2  + (size_t)HID * OUTD / 2;   // bf16 N_N*HID
constexpr size_t OFF_OUT1 = OFF_H1   + (size_t)N_N * HID / 2;
constexpr size_t OFF_H2   = OFF_OUT1 + (size_t)N_N * HID / 2;    // bf16 N_N*OUTD
constexpr size_t OFF_OUT2 = OFF_H2   + (size_t)N_N * OUTD / 2;
constexpr size_t OFF_AS1  = OFF_OUT2 + (size_t)N_N * OUTD / 2;   // fp32 N_N*4
constexpr size_t OFF_AD1  = OFF_AS1  + (size_t)N_N * H1;
constexpr size_t OFF_AS2  = OFF_AD1  + (size_t)N_N * H1;         // fp32 N_N
constexpr size_t OFF_AD2  = OFF_AS2  + (size_t)N_N;
constexpr size_t OFF_ROWP = OFF_AD2  + (size_t)N_N;              // int N_N+1
constexpr size_t OFF_COL  = OFF_ROWP + (size_t)(N_N + 1);        // int N_ET
constexpr size_t OFF_WCUR = OFF_COL  + (size_t)N_ET;             // int N_N
// zeroed region (one memset): cnt + acc partials
constexpr size_t OFF_CNT  = OFF_WCUR + (size_t)N_N;              // int N_N
constexpr size_t OFF_ACC1 = OFF_CNT  + (size_t)N_N;              // 32*512 fp32
constexpr size_t OFF_ACC2 = OFF_ACC1 + (size_t)NPART * 512;      // 32*256 fp32
constexpr size_t OFF_ZEND = OFF_ACC2 + (size_t)NPART * 256;
// not zeroed (fully overwritten before read)
constexpr size_t OFF_W1   = OFF_ZEND;                            // fp32 N_ET*4
constexpr size_t OFF_W2   = OFF_W1 + (size_t)N_ET * 4;           // fp32 N_ET

extern "C" void kernel_launch(void* const* d_in, const int* in_sizes, int n_in,
                              void* d_out, int out_size, void* d_ws, size_t ws_size,
                              hipStream_t stream) {
  const float* x      = (const float*)d_in[0];
  const int*   ei     = (const int*)d_in[1];
  const float* W1     = (const float*)d_in[2];
  const float* asrc1  = (const float*)d_in[3];
  const float* adst1  = (const float*)d_in[4];
  // d_in[5] = bias1 (cancels under BN)
  const float* g1     = (const float*)d_in[6];
  const float* b1     = (const float*)d_in[7];
  const float* W2     = (const float*)d_in[8];
  const float* asrc2  = (const float*)d_in[9];
  const float* adst2  = (const float*)d_in[10];
  // d_in[11] = bias2 (cancels under BN)
  const float* g2     = (const float*)d_in[12];
  const float* b2     = (const float*)d_in[13];

  float* ws = (float*)d_ws;
  u16*   wp1   = (u16*)(ws + OFF_WP1);
  u16*   wp2   = (u16*)(ws + OFF_WP2);
  u16*   h1    = (u16*)(ws + OFF_H1);
  u16*   out1  = (u16*)(ws + OFF_OUT1);
  u16*   h2    = (u16*)(ws + OFF_H2);
  u16*   out2  = (u16*)(ws + OFF_OUT2);
  float* as1   = ws + OFF_AS1;
  float* ad1   = ws + OFF_AD1;
  float* as2   = ws + OFF_AS2;
  float* ad2   = ws + OFF_AD2;
  int*   rowp  = (int*)(ws + OFF_ROWP);
  int*   col   = (int*)(ws + OFF_COL);
  int*   wcur  = (int*)(ws + OFF_WCUR);
  int*   cnt   = (int*)(ws + OFF_CNT);
  float* acc1p = ws + OFF_ACC1;
  float* acc2p = ws + OFF_ACC2;
  float* w1e   = ws + OFF_W1;
  float* w2e   = ws + OFF_W2;
  float* outf  = (float*)d_out;

  // zero: cnt + acc partials (contiguous, ~178 KB)
  hipMemsetAsync(cnt, 0, (OFF_ZEND - OFF_CNT) * sizeof(float), stream);

  const int eb = (N_ET + 255) / 256;   // 1329
  // 1. W packs + degree histogram
  prep_k<<<eb, 256, 0, stream>>>(ei, W1, W2, wp1, wp2, cnt);
  // 2. exclusive scan -> rowptr/wcur
  scan_k<<<1, 1024, 0, stream>>>(cnt, rowp, wcur);
  // 3. CSR scatter + GEMM1(+alpha1) fused
  sg_k<<<GB1 + eb, 256, 0, stream>>>(x, wp1, asrc1, adst1, h1, as1, ad1, ei, wcur, col);
  // 3b. layer-1 edge weights (softmax numerators)
  wgen_k<H1><<<N_N / 4, 256, 0, stream>>>(rowp, col, as1, ad1, w1e);
  // 4. layer-1 edge softmax + aggregate + BN1 stats partials
  gat_agg1_k<<<N_N / 4, 256, 0, stream>>>(rowp, col, h1, w1e, out1, acc1p);
  // 5. GEMM2 (BN1 finalize + BN1/ELU on A, fused alpha2)
  gemm2_mfma_k<<<N_N / 32, 256, 0, stream>>>(out1, acc1p, g1, b1, wp2, asrc2, adst2, h2, as2, ad2);
  // 5b. layer-2 edge weights
  wgen_k<1><<<N_N / 4, 256, 0, stream>>>(rowp, col, as2, ad2, w2e);
  // 6. layer-2 edge softmax + aggregate + BN2 stats partials
  gat_agg2_k<<<N_N / 4, 256, 0, stream>>>(rowp, col, h2, w2e, out2, acc2p);
  // 7. BN2 finalize + apply -> fp32 output
  apply_k<<<512, 256, 0, stream>>>(out2, acc2p, g2, b2, outf);
}

// Round 9
// 228.918 us; speedup vs baseline: 1.1308x; 1.0259x over previous
//
#include <hip/hip_runtime.h>
#include <type_traits>

constexpr int N_N  = 20000;
constexpr int N_E  = 320000;
constexpr int N_ET = N_E + N_N;   // 340000 (self-loops appended)
constexpr int IN_D = 128;
constexpr int HID  = 256;
constexpr int H1   = 4;           // heads layer 1
constexpr int OUTD = 128;
constexpr float SLOPE = 0.2f;
constexpr float BNEPS = 1e-5f;
constexpr int NPART = 32;         // BN partial buffers (contention limiter)

typedef unsigned short u16;
typedef float f32x4 __attribute__((ext_vector_type(4)));
typedef short bf16x8 __attribute__((ext_vector_type(8)));
typedef unsigned short u16x8 __attribute__((ext_vector_type(8)));

__device__ __forceinline__ float bf2f(u16 u) { return __uint_as_float((unsigned)u << 16); }
__device__ __forceinline__ u16 f2bf(float f) {
  unsigned u = __float_as_uint(f);
  unsigned r = u + 0x7FFFu + ((u >> 16) & 1u);  // RNE
  return (u16)(r >> 16);
}

// ---------------- prep: W1/W2 bf16 transpose-pack + degree histogram ----------------
__global__ __launch_bounds__(256) void prep_k(const int* __restrict__ ei,
                                              const float* __restrict__ W1,
                                              const float* __restrict__ W2,
                                              u16* __restrict__ wp1,
                                              u16* __restrict__ wp2,
                                              int* __restrict__ cnt) {
  const int i = blockIdx.x * 256 + threadIdx.x;
  if (i < IN_D * HID) {           // 32768
    const int n = i >> 7, k = i & 127;
    wp1[i] = f2bf(W1[(size_t)k * HID + n]);
  }
  if (i < HID * OUTD) {           // 32768
    const int n = i >> 8, k = i & 255;
    wp2[i] = f2bf(W2[(size_t)k * OUTD + n]);
  }
  if (i < N_ET) {
    const int dst = (i < N_E) ? ei[N_E + i] : (i - N_E);
    atomicAdd(&cnt[dst], 1);
  }
}

// ---------------- scan: 1 block, 1024 thr, shuffle wave-scan (2 barriers) ----------
__global__ __launch_bounds__(1024) void scan_k(const int* __restrict__ cnt,
                                               int* __restrict__ rowptr,
                                               int* __restrict__ wcur) {
  __shared__ int wsum[17];
  const int tid = threadIdx.x, lane = tid & 63, wv = tid >> 6;
  constexpr int CHK = 20;         // 1024*20 = 20480 >= 20000
  const int base = tid * CHK;
  int c[CHK];
  int s = 0;
#pragma unroll
  for (int j = 0; j < CHK; ++j) {
    const int idx = base + j;
    c[j] = (idx < N_N) ? cnt[idx] : 0;
    s += c[j];
  }
  const int own = s;
#pragma unroll
  for (int off = 1; off < 64; off <<= 1) {
    const int v = __shfl_up(s, off, 64);
    if (lane >= off) s += v;
  }
  if (lane == 63) wsum[wv] = s;
  __syncthreads();
  if (tid == 0) {
    int run = 0;
#pragma unroll
    for (int i = 0; i < 16; ++i) { const int t = wsum[i]; wsum[i] = run; run += t; }
    wsum[16] = run;
  }
  __syncthreads();
  int run = wsum[wv] + (s - own);
#pragma unroll
  for (int j = 0; j < CHK; ++j) {
    const int idx = base + j;
    if (idx < N_N) {
      rowptr[idx] = run;
      wcur[idx]   = run;
      run += c[j];
    }
  }
  if (tid == 0) rowptr[N_N] = wsum[16];
}

// ---------------- fused: CSR scatter (blocks >= GB1) + GEMM1 MFMA + alpha1 --------
constexpr int GB1 = N_N / 16;   // 1250 gemm blocks
__global__ __launch_bounds__(256) void sg_k(const float* __restrict__ x,
                                            const u16* __restrict__ wp,     // [256][128]
                                            const float* __restrict__ asrc,
                                            const float* __restrict__ adst,
                                            u16* __restrict__ h,            // [20000][256]
                                            float* __restrict__ as_,        // [20000][4]
                                            float* __restrict__ ad_,
                                            const int* __restrict__ ei,
                                            int* __restrict__ wcur,
                                            int* __restrict__ col) {
  const int tid = threadIdx.x;
  if (blockIdx.x >= GB1) {
    const int i = (blockIdx.x - GB1) * 256 + tid;
    if (i >= N_ET) return;
    int s, dst;
    if (i < N_E) { s = ei[i]; dst = ei[N_E + i]; } else { s = dst = i - N_E; }
    const int pos = atomicAdd(&wcur[dst], 1);
    col[pos] = s;
    return;
  }
  const int wv = tid >> 6, lane = tid & 63;
  const int q = lane >> 4, t = lane & 15;
  const int m0 = blockIdx.x * 16;
  const int n0 = wv * 64;
  f32x4 acc[4] = {};
#pragma unroll
  for (int kb = 0; kb < 4; ++kb) {
    const int k0 = kb * 32 + q * 8;
    const float4 x0 = *(const float4*)(x + (size_t)(m0 + t) * 128 + k0);
    const float4 x1 = *(const float4*)(x + (size_t)(m0 + t) * 128 + k0 + 4);
    bf16x8 a;
    a[0] = (short)f2bf(x0.x); a[1] = (short)f2bf(x0.y);
    a[2] = (short)f2bf(x0.z); a[3] = (short)f2bf(x0.w);
    a[4] = (short)f2bf(x1.x); a[5] = (short)f2bf(x1.y);
    a[6] = (short)f2bf(x1.z); a[7] = (short)f2bf(x1.w);
#pragma unroll
    for (int nt = 0; nt < 4; ++nt) {
      const int n = n0 + nt * 16 + t;
      const bf16x8 b = *(const bf16x8*)(wp + (size_t)n * 128 + k0);
      acc[nt] = __builtin_amdgcn_mfma_f32_16x16x32_bf16(a, b, acc[nt], 0, 0, 0);
    }
  }
  float ps[4] = {0.f, 0.f, 0.f, 0.f}, pd[4] = {0.f, 0.f, 0.f, 0.f};
#pragma unroll
  for (int nt = 0; nt < 4; ++nt) {
    const int coln = n0 + nt * 16 + t;
    const float a_s = asrc[coln], a_d = adst[coln];
#pragma unroll
    for (int r = 0; r < 4; ++r) {
      const float d = acc[nt][r];
      h[(size_t)(m0 + q * 4 + r) * 256 + coln] = f2bf(d);
      ps[r] += d * a_s;
      pd[r] += d * a_d;
    }
  }
#pragma unroll
  for (int off = 1; off < 16; off <<= 1)
#pragma unroll
    for (int r = 0; r < 4; ++r) {
      ps[r] += __shfl_xor(ps[r], off, 64);
      pd[r] += __shfl_xor(pd[r], off, 64);
    }
  if (t == 0) {
#pragma unroll
    for (int r = 0; r < 4; ++r) {
      const int row = m0 + q * 4 + r;
      as_[(size_t)row * 4 + wv] = ps[r];
      ad_[(size_t)row * 4 + wv] = pd[r];
    }
  }
}

// ---------------- agg layer 1: 1 wave per node, 16B/lane loads, 2-edge parity ------
// 32 lanes x 8 channels cover a row; lanes split into edge-parity halves (eh=lane>>5).
// Per 8-edge round: 4 load instrs (each covers 2 edges). Halves combined by xor32.
__global__ __launch_bounds__(256) void gat_agg1_k(const int* __restrict__ rowptr,
                                                  const int* __restrict__ col,
                                                  const u16* __restrict__ h,
                                                  const float* __restrict__ as_,
                                                  const float* __restrict__ ad_,
                                                  u16* __restrict__ out,
                                                  float* __restrict__ accp) {  // [32][512]
  __shared__ __align__(16) float s_w[4][64][4];
  __shared__ __align__(16) float st_s[4][256], st_q[4][256];
  const int tid = threadIdx.x;
  const int wv = tid >> 6, lane = tid & 63;
  const int n = blockIdx.x * 4 + wv;
  const int beg = rowptr[n], end = rowptr[n + 1];
  const int eh = lane >> 5;         // edge parity of this lane
  const int cp = lane & 31;
  const int c0 = cp * 8;            // 8-channel base
  const int hl = cp >> 3;           // head of these channels (64 ch per head)
  const float4 adv = *(const float4*)(ad_ + (size_t)n * 4);

  float a[8] = {};
  float smh = 0.f;

  for (int j0 = beg; j0 < end; j0 += 64) {
    const int cnt = min(64, end - j0);
    const int j = j0 + lane;
    const int sl = col[(j < end) ? j : beg];

    // issue batch-0 row loads immediately (indices via cross-lane shuffle)
    u16x8 gA[4];
#pragma unroll
    for (int u = 0; u < 4; ++u) {
      const int sv = __shfl(sl, 2 * u + eh, 64);
      gA[u] = *(const u16x8*)(h + (size_t)sv * 256 + c0);
    }

    // per-edge weights for all 4 heads (overlaps with gA in flight)
    const float4 av = *(const float4*)(as_ + (size_t)sl * 4);
    float e0 = av.x + adv.x; e0 = e0 > 0.f ? e0 : SLOPE * e0;
    float e1 = av.y + adv.y; e1 = e1 > 0.f ? e1 : SLOPE * e1;
    float e2 = av.z + adv.z; e2 = e2 > 0.f ? e2 : SLOPE * e2;
    float e3 = av.w + adv.w; e3 = e3 > 0.f ? e3 : SLOPE * e3;
    const bool valid = j < end;
    float4 w4;
    w4.x = valid ? __expf(e0) : 0.f;
    w4.y = valid ? __expf(e1) : 0.f;
    w4.z = valid ? __expf(e2) : 0.f;
    w4.w = valid ? __expf(e3) : 0.f;
    *(float4*)(&s_w[wv][lane][0]) = w4;
    // wave-synchronous LDS (same wave wrote it)

    const int rounds = (cnt + 7) >> 3;   // zero-weight padding beyond cnt
    for (int r = 0; r < rounds; ++r) {
      u16x8 gB[4];
      if (r + 1 < rounds) {
        const int nb = (r + 1) * 8;
#pragma unroll
        for (int u = 0; u < 4; ++u) {
          const int sv = __shfl(sl, nb + 2 * u + eh, 64);
          gB[u] = *(const u16x8*)(h + (size_t)sv * 256 + c0);
        }
      }
      const int rb = r * 8;
#pragma unroll
      for (int u = 0; u < 4; ++u) {
        const float w = s_w[wv][rb + 2 * u + eh][hl];
        smh += w;
#pragma unroll
        for (int k = 0; k < 8; ++k) a[k] = fmaf(w, bf2f(gA[u][k]), a[k]);
      }
      if (r + 1 < rounds) {
#pragma unroll
        for (int u = 0; u < 4; ++u) gA[u] = gB[u];
      }
    }
  }

  // combine edge-parity halves (aggregation is linear)
  smh += __shfl_xor(smh, 32, 64);
#pragma unroll
  for (int k = 0; k < 8; ++k) a[k] += __shfl_xor(a[k], 32, 64);

  const float rr = 1.f / (smh + 1e-16f);
  float v[8];
#pragma unroll
  for (int k = 0; k < 8; ++k) v[k] = a[k] * rr;

  if (lane < 32) {
    u16x8 o;
#pragma unroll
    for (int k = 0; k < 8; ++k) o[k] = f2bf(v[k]);
    *(u16x8*)(out + (size_t)n * 256 + c0) = o;
    float4 s0, s1, q0, q1;
    s0.x = v[0]; s0.y = v[1]; s0.z = v[2]; s0.w = v[3];
    s1.x = v[4]; s1.y = v[5]; s1.z = v[6]; s1.w = v[7];
    q0.x = v[0]*v[0]; q0.y = v[1]*v[1]; q0.z = v[2]*v[2]; q0.w = v[3]*v[3];
    q1.x = v[4]*v[4]; q1.y = v[5]*v[5]; q1.z = v[6]*v[6]; q1.w = v[7]*v[7];
    *(float4*)(&st_s[wv][c0])     = s0;
    *(float4*)(&st_s[wv][c0 + 4]) = s1;
    *(float4*)(&st_q[wv][c0])     = q0;
    *(float4*)(&st_q[wv][c0 + 4]) = q1;
  }
  __syncthreads();
  {
    const int c = tid;   // 256 channels
    const float s = st_s[0][c] + st_s[1][c] + st_s[2][c] + st_s[3][c];
    const float q = st_q[0][c] + st_q[1][c] + st_q[2][c] + st_q[3][c];
    float* dst = accp + (size_t)(blockIdx.x & (NPART - 1)) * 512;
    atomicAdd(&dst[c], s);
    atomicAdd(&dst[256 + c], q);
  }
}

// ---------------- agg layer 2: 1 wave per node, 16B/lane loads, 4-edge parity ------
// 16 lanes x 8 channels cover a row; 4 parity groups (eh=lane>>4). xor16+xor32 combine.
__global__ __launch_bounds__(256) void gat_agg2_k(const int* __restrict__ rowptr,
                                                  const int* __restrict__ col,
                                                  const u16* __restrict__ h,
                                                  const float* __restrict__ as_,
                                                  const float* __restrict__ ad_,
                                                  u16* __restrict__ out,
                                                  float* __restrict__ accp) {  // [32][256]
  __shared__ __align__(16) float st_s[4][128], st_q[4][128];
  const int tid = threadIdx.x;
  const int wv = tid >> 6, lane = tid & 63;
  const int n = blockIdx.x * 4 + wv;
  const int beg = rowptr[n], end = rowptr[n + 1];
  const int eh = lane >> 4;          // 4-way edge parity
  const int cp = lane & 15;
  const int c0 = cp * 8;             // 8-channel base within 128
  const float adv = ad_[n];

  float a[8] = {};
  float smh = 0.f;

  for (int j0 = beg; j0 < end; j0 += 64) {
    const int cnt = min(64, end - j0);
    const int j = j0 + lane;
    const int sl = col[(j < end) ? j : beg];
    float e = as_[sl] + adv;
    e = e > 0.f ? e : SLOPE * e;
    const float ew = (j < end) ? __expf(e) : 0.f;

    const int rounds = (cnt + 15) >> 4;   // 16 edges per round
    u16x8 gA[4];
#pragma unroll
    for (int u = 0; u < 4; ++u) {
      const int sv = __shfl(sl, 4 * u + eh, 64);
      gA[u] = *(const u16x8*)(h + (size_t)sv * 128 + c0);
    }
    for (int r = 0; r < rounds; ++r) {
      u16x8 gB[4];
      if (r + 1 < rounds) {
        const int nb = (r + 1) * 16;
#pragma unroll
        for (int u = 0; u < 4; ++u) {
          const int sv = __shfl(sl, nb + 4 * u + eh, 64);
          gB[u] = *(const u16x8*)(h + (size_t)sv * 128 + c0);
        }
      }
      const int rb = r * 16;
#pragma unroll
      for (int u = 0; u < 4; ++u) {
        const float w = __shfl(ew, rb + 4 * u + eh, 64);
        smh += w;
#pragma unroll
        for (int k = 0; k < 8; ++k) a[k] = fmaf(w, bf2f(gA[u][k]), a[k]);
      }
      if (r + 1 < rounds) {
#pragma unroll
        for (int u = 0; u < 4; ++u) gA[u] = gB[u];
      }
    }
  }

  // combine 4 parity groups (aggregation is linear)
  smh += __shfl_xor(smh, 16, 64);
  smh += __shfl_xor(smh, 32, 64);
#pragma unroll
  for (int k = 0; k < 8; ++k) {
    a[k] += __shfl_xor(a[k], 16, 64);
    a[k] += __shfl_xor(a[k], 32, 64);
  }

  const float rr = 1.f / (smh + 1e-16f);
  float v[8];
#pragma unroll
  for (int k = 0; k < 8; ++k) v[k] = a[k] * rr;

  if (lane < 16) {
    u16x8 o;
#pragma unroll
    for (int k = 0; k < 8; ++k) o[k] = f2bf(v[k]);
    *(u16x8*)(out + (size_t)n * 128 + c0) = o;
    float4 s0, s1, q0, q1;
    s0.x = v[0]; s0.y = v[1]; s0.z = v[2]; s0.w = v[3];
    s1.x = v[4]; s1.y = v[5]; s1.z = v[6]; s1.w = v[7];
    q0.x = v[0]*v[0]; q0.y = v[1]*v[1]; q0.z = v[2]*v[2]; q0.w = v[3]*v[3];
    q1.x = v[4]*v[4]; q1.y = v[5]*v[5]; q1.z = v[6]*v[6]; q1.w = v[7]*v[7];
    *(float4*)(&st_s[wv][c0])     = s0;
    *(float4*)(&st_s[wv][c0 + 4]) = s1;
    *(float4*)(&st_q[wv][c0])     = q0;
    *(float4*)(&st_q[wv][c0 + 4]) = q1;
  }
  __syncthreads();
  if (tid < 128) {
    const int c = tid;
    const float s = st_s[0][c] + st_s[1][c] + st_s[2][c] + st_s[3][c];
    const float q = st_q[0][c] + st_q[1][c] + st_q[2][c] + st_q[3][c];
    float* dst = accp + (size_t)(blockIdx.x & (NPART - 1)) * 256;
    atomicAdd(&dst[c], s);
    atomicAdd(&dst[128 + c], q);
  }
}

// ---------------- GEMM2 (MFMA) + BN1 finalize-from-partials + ELU on A + alpha2 ----
__global__ __launch_bounds__(256) void gemm2_mfma_k(const u16* __restrict__ hin,
                                                    const float* __restrict__ accp, // [32][512]
                                                    const float* __restrict__ g1,
                                                    const float* __restrict__ b1,
                                                    const u16* __restrict__ wp,   // [128][256]
                                                    const float* __restrict__ asrc,
                                                    const float* __restrict__ adst,
                                                    u16* __restrict__ h2,
                                                    float* __restrict__ as_,
                                                    float* __restrict__ ad_) {
  __shared__ float scsh[512];
  __shared__ float red[2][32][2];
  const int tid = threadIdx.x;
  {  // BN1 finalize: sum 32 partials per channel
    float s = 0.f, q = 0.f;
#pragma unroll
    for (int p = 0; p < NPART; ++p) {
      s += accp[(size_t)p * 512 + tid];
      q += accp[(size_t)p * 512 + 256 + tid];
    }
    const float mean = s * (1.f / N_N);
    const float var  = q * (1.f / N_N) - mean * mean;
    const float inv  = rsqrtf(var + BNEPS);
    const float sc   = g1[tid] * inv;
    scsh[tid]       = sc;
    scsh[256 + tid] = b1[tid] - mean * sc;
  }
  __syncthreads();
  const int wv = tid >> 6, lane = tid & 63;
  const int q = lane >> 4, t = lane & 15;
  const int mh = wv >> 1, nh = wv & 1;
  const int m0 = blockIdx.x * 32 + mh * 16;
  const int n0 = nh * 64;
  f32x4 acc[4] = {};
#pragma unroll
  for (int kb = 0; kb < 8; ++kb) {
    const int k0 = kb * 32 + q * 8;
    const ushort4 u0 = *(const ushort4*)(hin + (size_t)(m0 + t) * 256 + k0);
    const ushort4 u1 = *(const ushort4*)(hin + (size_t)(m0 + t) * 256 + k0 + 4);
    const float4 sc0 = *(const float4*)(scsh + k0);
    const float4 sc1 = *(const float4*)(scsh + k0 + 4);
    const float4 sh0 = *(const float4*)(scsh + 256 + k0);
    const float4 sh1 = *(const float4*)(scsh + 256 + k0 + 4);
    float v[8];
    v[0] = bf2f(u0.x) * sc0.x + sh0.x;
    v[1] = bf2f(u0.y) * sc0.y + sh0.y;
    v[2] = bf2f(u0.z) * sc0.z + sh0.z;
    v[3] = bf2f(u0.w) * sc0.w + sh0.w;
    v[4] = bf2f(u1.x) * sc1.x + sh1.x;
    v[5] = bf2f(u1.y) * sc1.y + sh1.y;
    v[6] = bf2f(u1.z) * sc1.z + sh1.z;
    v[7] = bf2f(u1.w) * sc1.w + sh1.w;
    bf16x8 a;
#pragma unroll
    for (int j = 0; j < 8; ++j) {
      const float e = v[j] > 0.f ? v[j] : __expf(v[j]) - 1.f;
      a[j] = (short)f2bf(e);
    }
#pragma unroll
    for (int nt = 0; nt < 4; ++nt) {
      const int n = n0 + nt * 16 + t;
      const bf16x8 b = *(const bf16x8*)(wp + (size_t)n * 256 + k0);
      acc[nt] = __builtin_amdgcn_mfma_f32_16x16x32_bf16(a, b, acc[nt], 0, 0, 0);
    }
  }
  float ps[4] = {0.f, 0.f, 0.f, 0.f}, pd[4] = {0.f, 0.f, 0.f, 0.f};
#pragma unroll
  for (int nt = 0; nt < 4; ++nt) {
    const int coln = n0 + nt * 16 + t;
    const float a_s = asrc[coln], a_d = adst[coln];
#pragma unroll
    for (int r = 0; r < 4; ++r) {
      const float d = acc[nt][r];
      h2[(size_t)(m0 + q * 4 + r) * 128 + coln] = f2bf(d);
      ps[r] += d * a_s;
      pd[r] += d * a_d;
    }
  }
#pragma unroll
  for (int off = 1; off < 16; off <<= 1)
#pragma unroll
    for (int r = 0; r < 4; ++r) {
      ps[r] += __shfl_xor(ps[r], off, 64);
      pd[r] += __shfl_xor(pd[r], off, 64);
    }
  if (t == 0) {
#pragma unroll
    for (int r = 0; r < 4; ++r) {
      red[0][mh * 16 + q * 4 + r][nh] = ps[r];
      red[1][mh * 16 + q * 4 + r][nh] = pd[r];
    }
  }
  __syncthreads();
  if (tid < 32) {
    as_[(size_t)blockIdx.x * 32 + tid] = red[0][tid][0] + red[0][tid][1];
    ad_[(size_t)blockIdx.x * 32 + tid] = red[1][tid][0] + red[1][tid][1];
  }
}

// ---------------- BN2 finalize-from-partials + apply, bf16 -> fp32 out -------------
__global__ __launch_bounds__(256) void apply_k(const u16* __restrict__ X,
                                               const float* __restrict__ accp, // [32][256]
                                               const float* __restrict__ gamma,
                                               const float* __restrict__ beta,
                                               float* __restrict__ Y) {
  __shared__ float s_sc[128], s_sh[128];
  const int tid = threadIdx.x;
  if (tid < 128) {
    float s = 0.f, q = 0.f;
#pragma unroll
    for (int p = 0; p < NPART; ++p) {
      s += accp[(size_t)p * 256 + tid];
      q += accp[(size_t)p * 256 + 128 + tid];
    }
    const float mean = s * (1.f / N_N);
    const float var  = q * (1.f / N_N) - mean * mean;
    const float inv  = rsqrtf(var + BNEPS);
    const float sc   = gamma[tid] * inv;
    s_sc[tid] = sc;
    s_sh[tid] = beta[tid] - mean * sc;
  }
  __syncthreads();
  constexpr size_t TOT = (size_t)N_N * OUTD;
  for (size_t i = ((size_t)blockIdx.x * 256 + tid) * 4; i < TOT;
       i += (size_t)gridDim.x * 256 * 4) {
    const ushort4 u = *(const ushort4*)(X + i);
    const int c = (int)(i & 127);
    float4 o;
    o.x = bf2f(u.x) * s_sc[c]     + s_sh[c];
    o.y = bf2f(u.y) * s_sc[c + 1] + s_sh[c + 1];
    o.z = bf2f(u.z) * s_sc[c + 2] + s_sh[c + 2];
    o.w = bf2f(u.w) * s_sc[c + 3] + s_sh[c + 3];
    *(float4*)(Y + i) = o;
  }
}

// ---------------- workspace layout (4-byte element offsets) ----------------
constexpr size_t OFF_WP1  = 0;                                   // bf16 256*128
constexpr size_t OFF_WP2  = OFF_WP1  + (size_t)IN_D * HID / 2;
constexpr size_t OFF_H1   = OFF_WP2  + (size_t)HID * OUTD / 2;   // bf16 N_N*HID
constexpr size_t OFF_OUT1 = OFF_H1   + (size_t)N_N * HID / 2;
constexpr size_t OFF_H2   = OFF_OUT1 + (size_t)N_N * HID / 2;    // bf16 N_N*OUTD
constexpr size_t OFF_OUT2 = OFF_H2   + (size_t)N_N * OUTD / 2;
constexpr size_t OFF_AS1  = OFF_OUT2 + (size_t)N_N * OUTD / 2;   // fp32 N_N*4
constexpr size_t OFF_AD1  = OFF_AS1  + (size_t)N_N * H1;
constexpr size_t OFF_AS2  = OFF_AD1  + (size_t)N_N * H1;         // fp32 N_N
constexpr size_t OFF_AD2  = OFF_AS2  + (size_t)N_N;
constexpr size_t OFF_ROWP = OFF_AD2  + (size_t)N_N;              // int N_N+1
constexpr size_t OFF_COL  = OFF_ROWP + (size_t)(N_N + 1);        // int N_ET
constexpr size_t OFF_WCUR = OFF_COL  + (size_t)N_ET;             // int N_N
// zeroed region (one memset): cnt + acc partials
constexpr size_t OFF_CNT  = OFF_WCUR + (size_t)N_N;              // int N_N
constexpr size_t OFF_ACC1 = OFF_CNT  + (size_t)N_N;              // 32*512 fp32
constexpr size_t OFF_ACC2 = OFF_ACC1 + (size_t)NPART * 512;      // 32*256 fp32
constexpr size_t OFF_ZEND = OFF_ACC2 + (size_t)NPART * 256;

extern "C" void kernel_launch(void* const* d_in, const int* in_sizes, int n_in,
                              void* d_out, int out_size, void* d_ws, size_t ws_size,
                              hipStream_t stream) {
  const float* x      = (const float*)d_in[0];
  const int*   ei     = (const int*)d_in[1];
  const float* W1     = (const float*)d_in[2];
  const float* asrc1  = (const float*)d_in[3];
  const float* adst1  = (const float*)d_in[4];
  // d_in[5] = bias1 (cancels under BN)
  const float* g1     = (const float*)d_in[6];
  const float* b1     = (const float*)d_in[7];
  const float* W2     = (const float*)d_in[8];
  const float* asrc2  = (const float*)d_in[9];
  const float* adst2  = (const float*)d_in[10];
  // d_in[11] = bias2 (cancels under BN)
  const float* g2     = (const float*)d_in[12];
  const float* b2     = (const float*)d_in[13];

  float* ws = (float*)d_ws;
  u16*   wp1   = (u16*)(ws + OFF_WP1);
  u16*   wp2   = (u16*)(ws + OFF_WP2);
  u16*   h1    = (u16*)(ws + OFF_H1);
  u16*   out1  = (u16*)(ws + OFF_OUT1);
  u16*   h2    = (u16*)(ws + OFF_H2);
  u16*   out2  = (u16*)(ws + OFF_OUT2);
  float* as1   = ws + OFF_AS1;
  float* ad1   = ws + OFF_AD1;
  float* as2   = ws + OFF_AS2;
  float* ad2   = ws + OFF_AD2;
  int*   rowp  = (int*)(ws + OFF_ROWP);
  int*   col   = (int*)(ws + OFF_COL);
  int*   wcur  = (int*)(ws + OFF_WCUR);
  int*   cnt   = (int*)(ws + OFF_CNT);
  float* acc1p = ws + OFF_ACC1;
  float* acc2p = ws + OFF_ACC2;
  float* outf  = (float*)d_out;

  // zero: cnt + acc partials (contiguous, ~178 KB)
  hipMemsetAsync(cnt, 0, (OFF_ZEND - OFF_CNT) * sizeof(float), stream);

  const int eb = (N_ET + 255) / 256;   // 1329
  // 1. W packs + degree histogram
  prep_k<<<eb, 256, 0, stream>>>(ei, W1, W2, wp1, wp2, cnt);
  // 2. exclusive scan -> rowptr/wcur
  scan_k<<<1, 1024, 0, stream>>>(cnt, rowp, wcur);
  // 3. CSR scatter + GEMM1(+alpha1) fused
  sg_k<<<GB1 + eb, 256, 0, stream>>>(x, wp1, asrc1, adst1, h1, as1, ad1, ei, wcur, col);
  // 4. layer-1 edge softmax + aggregate + BN1 stats partials
  gat_agg1_k<<<N_N / 4, 256, 0, stream>>>(rowp, col, h1, as1, ad1, out1, acc1p);
  // 5. GEMM2 (BN1 finalize + BN1/ELU on A, fused alpha2)
  gemm2_mfma_k<<<N_N / 32, 256, 0, stream>>>(out1, acc1p, g1, b1, wp2, asrc2, adst2, h2, as2, ad2);
  // 6. layer-2 edge softmax + aggregate + BN2 stats partials
  gat_agg2_k<<<N_N / 4, 256, 0, stream>>>(rowp, col, h2, as2, ad2, out2, acc2p);
  // 7. BN2 finalize + apply -> fp32 output
  apply_k<<<512, 256, 0, stream>>>(out2, acc2p, g2, b2, outf);
}